// Round 1
// baseline (400.133 us; speedup 1.0000x reference)
//
#include <hip/hip_runtime.h>
#include <hip/hip_bf16.h>

// Problem constants (from reference setup): B=4,S=2048 -> T=8192 tokens, H=1024, E=8, TOP_K=2
#define H 1024
#define NEXP 8
#define T_TOK 8192
#define CAP 8192      // max entries per expert (<=1 entry per token per expert)
#define TM 128
#define TN 128
#define BK 32

typedef __bf16 bf16x8 __attribute__((ext_vector_type(8)));
typedef float f32x4 __attribute__((ext_vector_type(4)));

__device__ __forceinline__ void async16(void* lds, const void* g) {
    __builtin_amdgcn_global_load_lds(
        (const __attribute__((address_space(1))) void*)g,
        (__attribute__((address_space(3))) void*)lds, 16, 0, 0);
}

// ---------------- routing: logits (fp32), top-2, gates; fused x -> bf16 cast ----------------
__global__ __launch_bounds__(256) void moe_route(
    const float* __restrict__ x, const float* __restrict__ Wg,
    __bf16* __restrict__ Xb, int* __restrict__ cnt,
    int* __restrict__ ltok, float* __restrict__ lgate) {
    const int lane = threadIdx.x & 63;
    const int wave = threadIdx.x >> 6;
    const int t = blockIdx.x * 4 + wave;   // grid = T/4 blocks of 256
    const float* xr = x + (size_t)t * H;
    __bf16* xbr = Xb + (size_t)t * H;
    float a[NEXP];
#pragma unroll
    for (int e = 0; e < NEXP; ++e) a[e] = 0.f;
#pragma unroll
    for (int j = 0; j < H / 64; ++j) {
        const int h = j * 64 + lane;
        const float xv = xr[h];
        xbr[h] = (__bf16)xv;
        const float4 w0 = *(const float4*)(Wg + h * NEXP);
        const float4 w1 = *(const float4*)(Wg + h * NEXP + 4);
        a[0] += xv * w0.x; a[1] += xv * w0.y; a[2] += xv * w0.z; a[3] += xv * w0.w;
        a[4] += xv * w1.x; a[5] += xv * w1.y; a[6] += xv * w1.z; a[7] += xv * w1.w;
    }
#pragma unroll
    for (int e = 0; e < NEXP; ++e) {
#pragma unroll
        for (int off = 32; off > 0; off >>= 1)
            a[e] += __shfl_xor(a[e], off, 64);
    }
    if (lane == 0) {
        // top-2 with jax tie-break (lowest index first): strict > comparisons
        int i0 = 0;
#pragma unroll
        for (int e = 1; e < NEXP; ++e) if (a[e] > a[i0]) i0 = e;
        int i1 = (i0 == 0) ? 1 : 0;
#pragma unroll
        for (int e = 0; e < NEXP; ++e) if (e != i0 && a[e] > a[i1]) i1 = e;
        // gates = softmax over the two kept logits (== renormalized full softmax)
        const float ex = expf(a[i1] - a[i0]);   // a[i1] <= a[i0] -> stable
        const float g0 = 1.f / (1.f + ex);
        const float g1 = ex / (1.f + ex);
        int s0 = atomicAdd(&cnt[i0], 1);
        ltok[i0 * CAP + s0] = t; lgate[i0 * CAP + s0] = g0;
        int s1 = atomicAdd(&cnt[i1], 1);
        ltok[i1 * CAP + s1] = t; lgate[i1 * CAP + s1] = g1;
    }
}

// ---------------- We (E,h,d) fp32 -> WeT (E,d,h) bf16 : B^T for contiguous B-fragments ----------------
__global__ __launch_bounds__(256) void cast_transpose_we(
    const float* __restrict__ We, __bf16* __restrict__ WeT) {
    __shared__ float tile[32][33];
    const int e = blockIdx.z;
    const int d0 = blockIdx.x * 32;
    const int h0 = blockIdx.y * 32;
    const int tx = threadIdx.x & 31;
    const int ty = threadIdx.x >> 5;   // 0..7
    const float* src = We + ((size_t)e << 20);
    __bf16* dst = WeT + ((size_t)e << 20);
#pragma unroll
    for (int r = 0; r < 4; ++r)
        tile[ty + r * 8][tx] = src[(size_t)(h0 + ty + r * 8) * H + d0 + tx];
    __syncthreads();
#pragma unroll
    for (int r = 0; r < 4; ++r)
        dst[(size_t)(d0 + ty + r * 8) * H + h0 + tx] = (__bf16)tile[tx][ty + r * 8];
}

// ---------------- grouped GEMM: per expert, gathered-token rows, 128x128 tile, bf16 MFMA ----------------
__global__ __launch_bounds__(256) void moe_gemm(
    const __bf16* __restrict__ Xb, const __bf16* __restrict__ WeT,
    const float* __restrict__ be, const int* __restrict__ cnt,
    const int* __restrict__ ltok, const float* __restrict__ lgate,
    float* __restrict__ out) {
    const int e = blockIdx.z;
    const int ne = cnt[e];
    const int m0 = blockIdx.y * TM;
    if (m0 >= ne) return;              // uniform early-exit for empty tiles
    const int n0 = blockIdx.x * TN;

    __shared__ __align__(16) __bf16 Al[TM * BK];
    __shared__ __align__(16) __bf16 Bl[TN * BK];
    __shared__ int tokL[TM];
    __shared__ float gateL[TM];

    const int tid = threadIdx.x;
    const int lane = tid & 63;
    const int wave = tid >> 6;

    if (tid < TM) {
        const int gi = m0 + tid;
        tokL[tid]  = (gi < ne) ? ltok[e * CAP + gi] : 0;   // pad rows read token 0, discarded in epilogue
        gateL[tid] = (gi < ne) ? lgate[e * CAP + gi] : 0.f;
    }
    __syncthreads();

    const __bf16* Bt = WeT + ((size_t)e << 20);
    const int qr = lane >> 4;          // quad 0..3
    const int rr = lane & 15;
    const int wr = (wave >> 1) * 64;   // wave's 64x64 quadrant
    const int wc = (wave & 1) * 64;

    f32x4 acc[4][4];
    const f32x4 z = {0.f, 0.f, 0.f, 0.f};
#pragma unroll
    for (int i = 0; i < 4; ++i)
#pragma unroll
        for (int j = 0; j < 4; ++j) acc[i][j] = z;

    // thread -> two 16B chunks; within a wave lanes cover consecutive LDS 16B slots (global_load_lds req.)
    const int c0 = tid, c1 = tid + 256;
    const int ar0 = c0 >> 2, ak0 = (c0 & 3) * 8;
    const int ar1 = c1 >> 2, ak1 = (c1 & 3) * 8;
    const size_t arow0 = (size_t)tokL[ar0] * H;
    const size_t arow1 = (size_t)tokL[ar1] * H;
    const size_t brow0 = (size_t)(n0 + ar0) * H;
    const size_t brow1 = (size_t)(n0 + ar1) * H;

    for (int k0 = 0; k0 < H; k0 += BK) {
        async16(&Al[c0 * 8], Xb + arow0 + k0 + ak0);
        async16(&Al[c1 * 8], Xb + arow1 + k0 + ak1);
        async16(&Bl[c0 * 8], Bt + brow0 + k0 + ak0);
        async16(&Bl[c1 * 8], Bt + brow1 + k0 + ak1);
        __syncthreads();
        bf16x8 af[4], bfr[4];
#pragma unroll
        for (int i = 0; i < 4; ++i)
            af[i] = *(const bf16x8*)&Al[(wr + i * 16 + rr) * BK + qr * 8];
#pragma unroll
        for (int j = 0; j < 4; ++j)
            bfr[j] = *(const bf16x8*)&Bl[(wc + j * 16 + rr) * BK + qr * 8];
#pragma unroll
        for (int i = 0; i < 4; ++i)
#pragma unroll
            for (int j = 0; j < 4; ++j)
                acc[i][j] = __builtin_amdgcn_mfma_f32_16x16x32_bf16(af[i], bfr[j], acc[i][j], 0, 0, 0);
        __syncthreads();
    }

    float bev[4];
#pragma unroll
    for (int j = 0; j < 4; ++j) bev[j] = be[e * H + n0 + wc + j * 16 + rr];

    // C/D layout (verified m89/m91): col = lane&15, row = quad*4 + reg
#pragma unroll
    for (int i = 0; i < 4; ++i) {
#pragma unroll
        for (int reg = 0; reg < 4; ++reg) {
            const int rloc = wr + i * 16 + qr * 4 + reg;
            if (m0 + rloc < ne) {
                const int t = tokL[rloc];
                const float g = gateL[rloc];
                float* orow = out + (size_t)t * H;
#pragma unroll
                for (int j = 0; j < 4; ++j) {
                    const int d = n0 + wc + j * 16 + rr;
                    atomicAdd(&orow[d], g * (acc[i][j][reg] + bev[j]));
                }
            }
        }
    }
}

extern "C" void kernel_launch(void* const* d_in, const int* in_sizes, int n_in,
                              void* d_out, int out_size, void* d_ws, size_t ws_size,
                              hipStream_t stream) {
    const float* x  = (const float*)d_in[0];   // (T,H) fp32
    const float* Wg = (const float*)d_in[1];   // (H,E) fp32
    const float* We = (const float*)d_in[2];   // (E,H,H) fp32
    const float* be = (const float*)d_in[3];   // (E,H) fp32
    float* out = (float*)d_out;

    // workspace layout (~33.6 MiB): Xb 16MiB | WeT 16MiB | cnt | token lists | gate lists
    char* ws = (char*)d_ws;
    __bf16* Xb   = (__bf16*)ws;
    __bf16* WeT  = (__bf16*)(ws + ((size_t)16 << 20));
    int*    cnt  = (int*)(ws + ((size_t)32 << 20));
    int*    ltok = (int*)(ws + ((size_t)32 << 20) + 256);
    float*  lgat = (float*)(ws + ((size_t)32 << 20) + 256 + (size_t)NEXP * CAP * 4);

    hipMemsetAsync(cnt, 0, NEXP * sizeof(int), stream);
    hipMemsetAsync(d_out, 0, (size_t)out_size * sizeof(float), stream);

    cast_transpose_we<<<dim3(H / 32, H / 32, NEXP), 256, 0, stream>>>(We, WeT);
    moe_route<<<T_TOK / 4, 256, 0, stream>>>(x, Wg, Xb, cnt, ltok, lgat);
    moe_gemm<<<dim3(H / TN, T_TOK / TM, NEXP), 256, 0, stream>>>(Xb, WeT, be, cnt, ltok, lgat, out);
}

// Round 2
// 235.011 us; speedup vs baseline: 1.7026x; 1.7026x over previous
//
#include <hip/hip_runtime.h>
#include <hip/hip_bf16.h>

// Problem constants (from reference setup): B=4,S=2048 -> T=8192 tokens, H=1024, E=8, TOP_K=2
#define H 1024
#define NEXP 8
#define T_TOK 8192
#define CAP 8192      // max entries per expert (<=1 entry per token per expert)
#define TM 128
#define TN 128
#define BK 32
#define TPB 32        // tokens routed per block in moe_route

typedef __bf16 bf16x8 __attribute__((ext_vector_type(8)));
typedef float f32x4 __attribute__((ext_vector_type(4)));

__device__ __forceinline__ void async16(void* lds, const void* g) {
    __builtin_amdgcn_global_load_lds(
        (const __attribute__((address_space(1))) void*)g,
        (__attribute__((address_space(3))) void*)lds, 16, 0, 0);
}

// ---------------- routing: logits (fp32), top-2, gates; fused x -> bf16 cast ----------------
// Block handles TPB tokens (8 per wave). Slot allocation is LDS-aggregated:
// <=8 global atomics per block instead of 2 per token (R1: 16384 same-address
// device atomics serialized -> 198us @ 2.7% VALUBusy).
__global__ __launch_bounds__(256) void moe_route(
    const float* __restrict__ x, const float* __restrict__ Wg,
    __bf16* __restrict__ Xb, int* __restrict__ cnt,
    int* __restrict__ ltok, float* __restrict__ lgate) {
    const int tid  = threadIdx.x;
    const int lane = tid & 63;
    const int wave = tid >> 6;
    const int base = blockIdx.x * TPB;

    __shared__ int   sE[TPB * 2];
    __shared__ float sG[TPB * 2];
    __shared__ int   lcnt[NEXP], lbase[NEXP], lslot[TPB * 2];

    for (int i = 0; i < TPB / 4; ++i) {          // 8 tokens per wave, sequential
        const int tl = wave * (TPB / 4) + i;
        const int t  = base + tl;
        const float* xr  = x  + (size_t)t * H;
        __bf16*      xbr = Xb + (size_t)t * H;
        float a[NEXP];
#pragma unroll
        for (int e = 0; e < NEXP; ++e) a[e] = 0.f;
#pragma unroll
        for (int j = 0; j < H / 64; ++j) {
            const int h = j * 64 + lane;
            const float xv = xr[h];
            xbr[h] = (__bf16)xv;
            const float4 w0 = *(const float4*)(Wg + h * NEXP);
            const float4 w1 = *(const float4*)(Wg + h * NEXP + 4);
            a[0] += xv * w0.x; a[1] += xv * w0.y; a[2] += xv * w0.z; a[3] += xv * w0.w;
            a[4] += xv * w1.x; a[5] += xv * w1.y; a[6] += xv * w1.z; a[7] += xv * w1.w;
        }
#pragma unroll
        for (int e = 0; e < NEXP; ++e) {
#pragma unroll
            for (int off = 32; off > 0; off >>= 1)
                a[e] += __shfl_xor(a[e], off, 64);
        }
        // all lanes hold identical sums; compute top-2 redundantly (no divergence)
        int i0 = 0;
#pragma unroll
        for (int e = 1; e < NEXP; ++e) if (a[e] > a[i0]) i0 = e;   // jax tie-break: lowest idx
        int i1 = (i0 == 0) ? 1 : 0;
#pragma unroll
        for (int e = 0; e < NEXP; ++e) if (e != i0 && a[e] > a[i1]) i1 = e;
        const float ex = __expf(a[i1] - a[i0]);   // a[i1] <= a[i0] -> stable
        const float g0 = 1.f / (1.f + ex);
        const float g1 = ex / (1.f + ex);
        if (lane == 0) {
            sE[tl * 2] = i0; sE[tl * 2 + 1] = i1;
            sG[tl * 2] = g0; sG[tl * 2 + 1] = g1;
        }
    }
    if (tid < NEXP) lcnt[tid] = 0;
    __syncthreads();
    if (tid < TPB * 2) lslot[tid] = atomicAdd(&lcnt[sE[tid]], 1);   // LDS atomics: cheap
    __syncthreads();
    if (tid < NEXP) lbase[tid] = lcnt[tid] ? atomicAdd(&cnt[tid], lcnt[tid]) : 0;
    __syncthreads();
    if (tid < TPB * 2) {
        const int e = sE[tid];
        const int s = lbase[e] + lslot[tid];
        ltok[e * CAP + s]  = base + (tid >> 1);
        lgate[e * CAP + s] = sG[tid];
    }
}

// ---------------- We (E,h,d) fp32 -> WeT (E,d,h) bf16 : B^T for contiguous B-fragments ----------------
__global__ __launch_bounds__(256) void cast_transpose_we(
    const float* __restrict__ We, __bf16* __restrict__ WeT) {
    __shared__ float tile[32][33];
    const int e = blockIdx.z;
    const int d0 = blockIdx.x * 32;
    const int h0 = blockIdx.y * 32;
    const int tx = threadIdx.x & 31;
    const int ty = threadIdx.x >> 5;   // 0..7
    const float* src = We + ((size_t)e << 20);
    __bf16* dst = WeT + ((size_t)e << 20);
#pragma unroll
    for (int r = 0; r < 4; ++r)
        tile[ty + r * 8][tx] = src[(size_t)(h0 + ty + r * 8) * H + d0 + tx];
    __syncthreads();
#pragma unroll
    for (int r = 0; r < 4; ++r)
        dst[(size_t)(d0 + ty + r * 8) * H + h0 + tx] = (__bf16)tile[tx][ty + r * 8];
}

// ---------------- grouped GEMM: per expert, gathered-token rows, 128x128 tile, bf16 MFMA ----------------
__global__ __launch_bounds__(256) void moe_gemm(
    const __bf16* __restrict__ Xb, const __bf16* __restrict__ WeT,
    const float* __restrict__ be, const int* __restrict__ cnt,
    const int* __restrict__ ltok, const float* __restrict__ lgate,
    float* __restrict__ out) {
    const int e = blockIdx.z;
    const int ne = cnt[e];
    const int m0 = blockIdx.y * TM;
    if (m0 >= ne) return;              // uniform early-exit for empty tiles
    const int n0 = blockIdx.x * TN;

    __shared__ __align__(16) __bf16 Al[TM * BK];
    __shared__ __align__(16) __bf16 Bl[TN * BK];
    __shared__ int tokL[TM];
    __shared__ float gateL[TM];

    const int tid = threadIdx.x;
    const int lane = tid & 63;
    const int wave = tid >> 6;

    if (tid < TM) {
        const int gi = m0 + tid;
        tokL[tid]  = (gi < ne) ? ltok[e * CAP + gi] : 0;   // pad rows read token 0, discarded in epilogue
        gateL[tid] = (gi < ne) ? lgate[e * CAP + gi] : 0.f;
    }
    __syncthreads();

    const __bf16* Bt = WeT + ((size_t)e << 20);
    const int qr = lane >> 4;          // quad 0..3
    const int rr = lane & 15;
    const int wr = (wave >> 1) * 64;   // wave's 64x64 quadrant
    const int wc = (wave & 1) * 64;

    f32x4 acc[4][4];
    const f32x4 z = {0.f, 0.f, 0.f, 0.f};
#pragma unroll
    for (int i = 0; i < 4; ++i)
#pragma unroll
        for (int j = 0; j < 4; ++j) acc[i][j] = z;

    // thread -> two 16B chunks; within a wave lanes cover consecutive LDS 16B slots (global_load_lds req.)
    const int c0 = tid, c1 = tid + 256;
    const int ar0 = c0 >> 2, ak0 = (c0 & 3) * 8;
    const int ar1 = c1 >> 2, ak1 = (c1 & 3) * 8;
    const size_t arow0 = (size_t)tokL[ar0] * H;
    const size_t arow1 = (size_t)tokL[ar1] * H;
    const size_t brow0 = (size_t)(n0 + ar0) * H;
    const size_t brow1 = (size_t)(n0 + ar1) * H;

    for (int k0 = 0; k0 < H; k0 += BK) {
        async16(&Al[c0 * 8], Xb + arow0 + k0 + ak0);
        async16(&Al[c1 * 8], Xb + arow1 + k0 + ak1);
        async16(&Bl[c0 * 8], Bt + brow0 + k0 + ak0);
        async16(&Bl[c1 * 8], Bt + brow1 + k0 + ak1);
        __syncthreads();
        bf16x8 af[4], bfr[4];
#pragma unroll
        for (int i = 0; i < 4; ++i)
            af[i] = *(const bf16x8*)&Al[(wr + i * 16 + rr) * BK + qr * 8];
#pragma unroll
        for (int j = 0; j < 4; ++j)
            bfr[j] = *(const bf16x8*)&Bl[(wc + j * 16 + rr) * BK + qr * 8];
#pragma unroll
        for (int i = 0; i < 4; ++i)
#pragma unroll
            for (int j = 0; j < 4; ++j)
                acc[i][j] = __builtin_amdgcn_mfma_f32_16x16x32_bf16(af[i], bfr[j], acc[i][j], 0, 0, 0);
        __syncthreads();
    }

    float bev[4];
#pragma unroll
    for (int j = 0; j < 4; ++j) bev[j] = be[e * H + n0 + wc + j * 16 + rr];

    // C/D layout (verified m89/m91): col = lane&15, row = quad*4 + reg
#pragma unroll
    for (int i = 0; i < 4; ++i) {
#pragma unroll
        for (int reg = 0; reg < 4; ++reg) {
            const int rloc = wr + i * 16 + qr * 4 + reg;
            if (m0 + rloc < ne) {
                const int t = tokL[rloc];
                const float g = gateL[rloc];
                float* orow = out + (size_t)t * H;
#pragma unroll
                for (int j = 0; j < 4; ++j) {
                    const int d = n0 + wc + j * 16 + rr;
                    atomicAdd(&orow[d], g * (acc[i][j][reg] + bev[j]));
                }
            }
        }
    }
}

extern "C" void kernel_launch(void* const* d_in, const int* in_sizes, int n_in,
                              void* d_out, int out_size, void* d_ws, size_t ws_size,
                              hipStream_t stream) {
    const float* x  = (const float*)d_in[0];   // (T,H) fp32
    const float* Wg = (const float*)d_in[1];   // (H,E) fp32
    const float* We = (const float*)d_in[2];   // (E,H,H) fp32
    const float* be = (const float*)d_in[3];   // (E,H) fp32
    float* out = (float*)d_out;

    // workspace layout (~33.6 MiB): Xb 16MiB | WeT 16MiB | cnt | token lists | gate lists
    char* ws = (char*)d_ws;
    __bf16* Xb   = (__bf16*)ws;
    __bf16* WeT  = (__bf16*)(ws + ((size_t)16 << 20));
    int*    cnt  = (int*)(ws + ((size_t)32 << 20));
    int*    ltok = (int*)(ws + ((size_t)32 << 20) + 256);
    float*  lgat = (float*)(ws + ((size_t)32 << 20) + 256 + (size_t)NEXP * CAP * 4);

    hipMemsetAsync(cnt, 0, NEXP * sizeof(int), stream);
    hipMemsetAsync(d_out, 0, (size_t)out_size * sizeof(float), stream);

    cast_transpose_we<<<dim3(H / 32, H / 32, NEXP), 256, 0, stream>>>(We, WeT);
    moe_route<<<T_TOK / TPB, 256, 0, stream>>>(x, Wg, Xb, cnt, ltok, lgat);
    moe_gemm<<<dim3(H / TN, T_TOK / TM, NEXP), 256, 0, stream>>>(Xb, WeT, be, cnt, ltok, lgat, out);
}

// Round 3
// 205.911 us; speedup vs baseline: 1.9432x; 1.1413x over previous
//
#include <hip/hip_runtime.h>
#include <hip/hip_bf16.h>

// Problem constants (from reference setup): B=4,S=2048 -> T=8192 tokens, H=1024, E=8, TOP_K=2
#define H 1024
#define NEXP 8
#define T_TOK 8192
#define CAP 8192      // max entries per expert; also the (e,s) packing radix
#define TM 128
#define TN 128
#define BK 32
#define TPB 32        // tokens routed per block in moe_route

typedef __bf16 bf16x8 __attribute__((ext_vector_type(8)));
typedef __bf16 bf16x4 __attribute__((ext_vector_type(4)));
typedef float f32x4 __attribute__((ext_vector_type(4)));

__device__ __forceinline__ void async16(void* lds, const void* g) {
    __builtin_amdgcn_global_load_lds(
        (const __attribute__((address_space(1))) void*)g,
        (__attribute__((address_space(3))) void*)lds, 16, 0, 0);
}

// ---------------- routing: logits (fp32), top-2, gates; fused x -> bf16 cast ----------------
// LDS-aggregated slot allocation (R1: per-token device atomics were 198us).
// Also emits per-token (expert,slot) records + gates for the combine kernel.
__global__ __launch_bounds__(256) void moe_route(
    const float* __restrict__ x, const float* __restrict__ Wg,
    __bf16* __restrict__ Xb, int* __restrict__ cnt,
    int* __restrict__ ltok, float* __restrict__ lgate,
    int* __restrict__ tsel, float* __restrict__ tgate) {
    const int tid  = threadIdx.x;
    const int lane = tid & 63;
    const int wave = tid >> 6;
    const int base = blockIdx.x * TPB;

    __shared__ int   sE[TPB * 2];
    __shared__ float sG[TPB * 2];
    __shared__ int   lcnt[NEXP], lbase[NEXP], lslot[TPB * 2];

    for (int i = 0; i < TPB / 4; ++i) {          // 8 tokens per wave, sequential
        const int tl = wave * (TPB / 4) + i;
        const int t  = base + tl;
        const float* xr  = x  + (size_t)t * H;
        __bf16*      xbr = Xb + (size_t)t * H;
        float a[NEXP];
#pragma unroll
        for (int e = 0; e < NEXP; ++e) a[e] = 0.f;
#pragma unroll
        for (int j = 0; j < H / 64; ++j) {
            const int h = j * 64 + lane;
            const float xv = xr[h];
            xbr[h] = (__bf16)xv;
            const float4 w0 = *(const float4*)(Wg + h * NEXP);
            const float4 w1 = *(const float4*)(Wg + h * NEXP + 4);
            a[0] += xv * w0.x; a[1] += xv * w0.y; a[2] += xv * w0.z; a[3] += xv * w0.w;
            a[4] += xv * w1.x; a[5] += xv * w1.y; a[6] += xv * w1.z; a[7] += xv * w1.w;
        }
#pragma unroll
        for (int e = 0; e < NEXP; ++e) {
#pragma unroll
            for (int off = 32; off > 0; off >>= 1)
                a[e] += __shfl_xor(a[e], off, 64);
        }
        // all lanes hold identical sums; compute top-2 redundantly (no divergence)
        int i0 = 0;
#pragma unroll
        for (int e = 1; e < NEXP; ++e) if (a[e] > a[i0]) i0 = e;   // jax tie-break: lowest idx
        int i1 = (i0 == 0) ? 1 : 0;
#pragma unroll
        for (int e = 0; e < NEXP; ++e) if (e != i0 && a[e] > a[i1]) i1 = e;
        const float ex = __expf(a[i1] - a[i0]);   // a[i1] <= a[i0] -> stable
        const float g0 = 1.f / (1.f + ex);
        const float g1 = ex / (1.f + ex);
        if (lane == 0) {
            sE[tl * 2] = i0; sE[tl * 2 + 1] = i1;
            sG[tl * 2] = g0; sG[tl * 2 + 1] = g1;
        }
    }
    if (tid < NEXP) lcnt[tid] = 0;
    __syncthreads();
    if (tid < TPB * 2) lslot[tid] = atomicAdd(&lcnt[sE[tid]], 1);   // LDS atomics: cheap
    __syncthreads();
    if (tid < NEXP) lbase[tid] = lcnt[tid] ? atomicAdd(&cnt[tid], lcnt[tid]) : 0;
    __syncthreads();
    if (tid < TPB * 2) {
        const int e = sE[tid];
        const int s = lbase[e] + lslot[tid];
        const int t = base + (tid >> 1);
        ltok[e * CAP + s]  = t;
        lgate[e * CAP + s] = sG[tid];
        tsel[t * 2 + (tid & 1)]  = e * CAP + s;   // (expert, within-expert slot) record
        tgate[t * 2 + (tid & 1)] = sG[tid];
    }
}

// ---------------- We (E,h,d) fp32 -> WeT (E,d,h) bf16 : B^T for contiguous B-fragments ----------------
__global__ __launch_bounds__(256) void cast_transpose_we(
    const float* __restrict__ We, __bf16* __restrict__ WeT) {
    __shared__ float tile[32][33];
    const int e = blockIdx.z;
    const int d0 = blockIdx.x * 32;
    const int h0 = blockIdx.y * 32;
    const int tx = threadIdx.x & 31;
    const int ty = threadIdx.x >> 5;   // 0..7
    const float* src = We + ((size_t)e << 20);
    __bf16* dst = WeT + ((size_t)e << 20);
#pragma unroll
    for (int r = 0; r < 4; ++r)
        tile[ty + r * 8][tx] = src[(size_t)(h0 + ty + r * 8) * H + d0 + tx];
    __syncthreads();
#pragma unroll
    for (int r = 0; r < 4; ++r)
        dst[(size_t)(d0 + ty + r * 8) * H + h0 + tx] = (__bf16)tile[tx][ty + r * 8];
}

// ---------------- grouped GEMM: per expert, gathered rows, 128x128 tile, bf16 MFMA ----------------
// Epilogue: plain bf16 stores to compacted scratch Eout[off[e]+slot][d] (no atomics).
// LDS is XOR-swizzled (chunk ^= (row>>1)&3) to break the 8-way bank conflict of
// row-stride-64B ds_read_b128 (R2: 4.3M conflict cycles); residual 2-way is free (m136).
__global__ __launch_bounds__(256) void moe_gemm(
    const __bf16* __restrict__ Xb, const __bf16* __restrict__ WeT,
    const float* __restrict__ be, const int* __restrict__ cnt,
    const int* __restrict__ ltok, const float* __restrict__ lgate,
    __bf16* __restrict__ Eout) {
    const int e = blockIdx.z;
    const int ne = cnt[e];
    const int m0 = blockIdx.y * TM;
    if (m0 >= ne) return;              // uniform early-exit for empty tiles
    const int n0 = blockIdx.x * TN;
    int off = 0;
    for (int i2 = 0; i2 < e; ++i2) off += cnt[i2];   // per-expert scratch base (8 scalar loads)

    __shared__ __align__(16) __bf16 Al[TM * BK];
    __shared__ __align__(16) __bf16 Bl[TN * BK];
    __shared__ int tokL[TM];

    const int tid = threadIdx.x;
    const int lane = tid & 63;
    const int wave = tid >> 6;

    if (tid < TM) {
        const int gi = m0 + tid;
        tokL[tid] = (gi < ne) ? ltok[e * CAP + gi] : 0;   // pad rows read token 0, not stored
    }
    __syncthreads();

    const __bf16* Bt = WeT + ((size_t)e << 20);
    const int qr = lane >> 4;          // quad 0..3
    const int rr = lane & 15;
    const int wr = (wave >> 1) * 64;   // wave's 64x64 quadrant
    const int wc = (wave & 1) * 64;

    f32x4 acc[4][4];
    const f32x4 z = {0.f, 0.f, 0.f, 0.f};
#pragma unroll
    for (int i = 0; i < 4; ++i)
#pragma unroll
        for (int j = 0; j < 4; ++j) acc[i][j] = z;

    // thread -> two 16B chunks; lanes cover consecutive LDS 16B slots (global_load_lds req.);
    // the source k-chunk is XOR-swizzled so the swizzled layout lands via contiguous LDS writes
    const int c0 = tid, c1 = tid + 256;
    const int ar0 = c0 >> 2, ak0 = (((c0 & 3) ^ ((c0 >> 3) & 3)) * 8);
    const int ar1 = c1 >> 2, ak1 = (((c1 & 3) ^ ((c1 >> 3) & 3)) * 8);
    const size_t arow0 = (size_t)tokL[ar0] * H;
    const size_t arow1 = (size_t)tokL[ar1] * H;
    const size_t brow0 = (size_t)(n0 + ar0) * H;
    const size_t brow1 = (size_t)(n0 + ar1) * H;

    for (int k0 = 0; k0 < H; k0 += BK) {
        async16(&Al[c0 * 8], Xb + arow0 + k0 + ak0);
        async16(&Al[c1 * 8], Xb + arow1 + k0 + ak1);
        async16(&Bl[c0 * 8], Bt + brow0 + k0 + ak0);
        async16(&Bl[c1 * 8], Bt + brow1 + k0 + ak1);
        __syncthreads();
        bf16x8 af[4], bfr[4];
#pragma unroll
        for (int i = 0; i < 4; ++i) {
            const int ra = wr + i * 16 + rr;
            af[i] = *(const bf16x8*)&Al[ra * BK + ((qr ^ ((ra >> 1) & 3)) * 8)];
        }
#pragma unroll
        for (int j = 0; j < 4; ++j) {
            const int rb = wc + j * 16 + rr;
            bfr[j] = *(const bf16x8*)&Bl[rb * BK + ((qr ^ ((rb >> 1) & 3)) * 8)];
        }
#pragma unroll
        for (int i = 0; i < 4; ++i)
#pragma unroll
            for (int j = 0; j < 4; ++j)
                acc[i][j] = __builtin_amdgcn_mfma_f32_16x16x32_bf16(af[i], bfr[j], acc[i][j], 0, 0, 0);
        __syncthreads();
    }

    float bev[4];
#pragma unroll
    for (int j = 0; j < 4; ++j) bev[j] = be[e * H + n0 + wc + j * 16 + rr];

    // C/D layout (verified m89/m91): col = lane&15, row = quad*4 + reg
#pragma unroll
    for (int i = 0; i < 4; ++i) {
#pragma unroll
        for (int reg = 0; reg < 4; ++reg) {
            const int rloc = wr + i * 16 + qr * 4 + reg;
            if (m0 + rloc < ne) {
                __bf16* orow = Eout + (size_t)(off + m0 + rloc) * H;
#pragma unroll
                for (int j = 0; j < 4; ++j) {
                    const int d = n0 + wc + j * 16 + rr;
                    orow[d] = (__bf16)(acc[i][j][reg] + bev[j]);
                }
            }
        }
    }
}

// ---------------- combine: out[t] = g0*Eout[row0] + g1*Eout[row1], float4 stores ----------------
__global__ __launch_bounds__(256) void moe_combine(
    const __bf16* __restrict__ Eout, const int* __restrict__ cnt,
    const int* __restrict__ tsel, const float* __restrict__ tgate,
    float* __restrict__ out) {
    const int t = blockIdx.x;
    __shared__ int offs[NEXP];
    if (threadIdx.x < NEXP) {
        int o = 0;
        for (int i = 0; i < threadIdx.x; ++i) o += cnt[i];
        offs[threadIdx.x] = o;
    }
    __syncthreads();
    const int sel0 = tsel[t * 2],     sel1 = tsel[t * 2 + 1];
    const float g0 = tgate[t * 2],    g1   = tgate[t * 2 + 1];
    const int e0 = sel0 >> 13, s0 = sel0 & (CAP - 1);
    const int e1 = sel1 >> 13, s1 = sel1 & (CAP - 1);
    const __bf16* r0 = Eout + (size_t)(offs[e0] + s0) * H;
    const __bf16* r1 = Eout + (size_t)(offs[e1] + s1) * H;
    const int d = threadIdx.x * 4;
    const bf16x4 a = *(const bf16x4*)(r0 + d);
    const bf16x4 b = *(const bf16x4*)(r1 + d);
    float4 o;
    o.x = g0 * (float)a[0] + g1 * (float)b[0];
    o.y = g0 * (float)a[1] + g1 * (float)b[1];
    o.z = g0 * (float)a[2] + g1 * (float)b[2];
    o.w = g0 * (float)a[3] + g1 * (float)b[3];
    *(float4*)(out + (size_t)t * H + d) = o;
}

extern "C" void kernel_launch(void* const* d_in, const int* in_sizes, int n_in,
                              void* d_out, int out_size, void* d_ws, size_t ws_size,
                              hipStream_t stream) {
    const float* x  = (const float*)d_in[0];   // (T,H) fp32
    const float* Wg = (const float*)d_in[1];   // (H,E) fp32
    const float* We = (const float*)d_in[2];   // (E,H,H) fp32
    const float* be = (const float*)d_in[3];   // (E,H) fp32
    float* out = (float*)d_out;

    // workspace: Xb 16MiB | WeT 16MiB | Eout 32MiB | cnt | lists | per-token records  (~64.7MiB)
    char* ws = (char*)d_ws;
    __bf16* Xb   = (__bf16*)ws;
    __bf16* WeT  = (__bf16*)(ws + ((size_t)16 << 20));
    __bf16* Eout = (__bf16*)(ws + ((size_t)32 << 20));
    char*   meta = ws + ((size_t)64 << 20);
    int*    cnt  = (int*)meta;
    int*    ltok = (int*)(meta + 256);
    float*  lgat = (float*)(meta + 256 + (size_t)NEXP * CAP * 4);
    int*    tsel = (int*)(meta + 256 + (size_t)NEXP * CAP * 8);
    float*  tgat = (float*)(meta + 256 + (size_t)NEXP * CAP * 8 + (size_t)T_TOK * 8);

    hipMemsetAsync(cnt, 0, NEXP * sizeof(int), stream);

    cast_transpose_we<<<dim3(H / 32, H / 32, NEXP), 256, 0, stream>>>(We, WeT);
    moe_route<<<T_TOK / TPB, 256, 0, stream>>>(x, Wg, Xb, cnt, ltok, lgat, tsel, tgat);
    moe_gemm<<<dim3(H / TN, T_TOK / TM, NEXP), 256, 0, stream>>>(Xb, WeT, be, cnt, ltok, lgat, Eout);
    moe_combine<<<T_TOK, 256, 0, stream>>>(Eout, cnt, tsel, tgat, out);
}

// Round 4
// 201.431 us; speedup vs baseline: 1.9865x; 1.0222x over previous
//
#include <hip/hip_runtime.h>
#include <hip/hip_bf16.h>

// Problem constants: B=4,S=2048 -> T=8192 tokens, H=1024, E=8, TOP_K=2
#define H 1024
#define NEXP 8
#define T_TOK 8192
#define CAP 8192      // max entries per expert; also the (e,s) packing radix
#define TM 128
#define TN 128
#define BK 32
#define TPB 16        // tokens routed per block (4 per wave) -> 512 blocks
#define CNTSTRIDE 32  // cnt[e*CNTSTRIDE]: one 128B line per expert -> parallel RMW chains

typedef __bf16 bf16x8 __attribute__((ext_vector_type(8)));
typedef __bf16 bf16x4 __attribute__((ext_vector_type(4)));
typedef float f32x4 __attribute__((ext_vector_type(4)));

__device__ __forceinline__ void async16(void* lds, const void* g) {
    __builtin_amdgcn_global_load_lds(
        (const __attribute__((address_space(1))) void*)g,
        (__attribute__((address_space(3))) void*)lds, 16, 0, 0);
}

// ---------------- routing: fp32 logits, top-2, gates; fused x -> bf16 cast ----------------
// LDS-aggregated slot allocation; cnt padded to one cacheline/expert (R3: single-line
// atomics serialized into one 2048-link RMW chain ~25us).
__global__ __launch_bounds__(256) void moe_route(
    const float* __restrict__ x, const float* __restrict__ Wg,
    __bf16* __restrict__ Xb, int* __restrict__ cnt,
    int* __restrict__ ltok, float* __restrict__ lgate,
    int* __restrict__ tsel, float* __restrict__ tgate) {
    const int tid  = threadIdx.x;
    const int lane = tid & 63;
    const int wave = tid >> 6;
    const int base = blockIdx.x * TPB;

    __shared__ int   sE[TPB * 2];
    __shared__ float sG[TPB * 2];
    __shared__ int   lcnt[NEXP], lbase[NEXP], lslot[TPB * 2];

    for (int i = 0; i < TPB / 4; ++i) {          // 4 tokens per wave
        const int tl = wave * (TPB / 4) + i;
        const int t  = base + tl;
        const float* xr  = x  + (size_t)t * H;
        __bf16*      xbr = Xb + (size_t)t * H;
        float a[NEXP];
#pragma unroll
        for (int e = 0; e < NEXP; ++e) a[e] = 0.f;
#pragma unroll
        for (int j = 0; j < H / 256; ++j) {
            const int h = j * 256 + lane * 4;
            const float4 xv = *(const float4*)(xr + h);
            bf16x4 xo;
            xo[0] = (__bf16)xv.x; xo[1] = (__bf16)xv.y;
            xo[2] = (__bf16)xv.z; xo[3] = (__bf16)xv.w;
            *(bf16x4*)(xbr + h) = xo;
            const float xc[4] = {xv.x, xv.y, xv.z, xv.w};
#pragma unroll
            for (int c = 0; c < 4; ++c) {
                const float4 w0 = *(const float4*)(Wg + (h + c) * NEXP);
                const float4 w1 = *(const float4*)(Wg + (h + c) * NEXP + 4);
                a[0] += xc[c] * w0.x; a[1] += xc[c] * w0.y; a[2] += xc[c] * w0.z; a[3] += xc[c] * w0.w;
                a[4] += xc[c] * w1.x; a[5] += xc[c] * w1.y; a[6] += xc[c] * w1.z; a[7] += xc[c] * w1.w;
            }
        }
#pragma unroll
        for (int e = 0; e < NEXP; ++e) {
#pragma unroll
            for (int off = 32; off > 0; off >>= 1)
                a[e] += __shfl_xor(a[e], off, 64);
        }
        // all lanes hold identical sums; top-2 computed redundantly (no divergence)
        int i0 = 0;
#pragma unroll
        for (int e = 1; e < NEXP; ++e) if (a[e] > a[i0]) i0 = e;   // jax tie-break: lowest idx
        int i1 = (i0 == 0) ? 1 : 0;
#pragma unroll
        for (int e = 0; e < NEXP; ++e) if (e != i0 && a[e] > a[i1]) i1 = e;
        const float ex = __expf(a[i1] - a[i0]);   // a[i1] <= a[i0] -> stable
        const float g0 = 1.f / (1.f + ex);
        const float g1 = ex / (1.f + ex);
        if (lane == 0) {
            sE[tl * 2] = i0; sE[tl * 2 + 1] = i1;
            sG[tl * 2] = g0; sG[tl * 2 + 1] = g1;
        }
    }
    if (tid < NEXP) lcnt[tid] = 0;
    __syncthreads();
    if (tid < TPB * 2) lslot[tid] = atomicAdd(&lcnt[sE[tid]], 1);   // LDS atomics: cheap
    __syncthreads();
    if (tid < NEXP) lbase[tid] = lcnt[tid] ? atomicAdd(&cnt[tid * CNTSTRIDE], lcnt[tid]) : 0;
    __syncthreads();
    if (tid < TPB * 2) {
        const int e = sE[tid];
        const int s = lbase[e] + lslot[tid];
        const int t = base + (tid >> 1);
        ltok[e * CAP + s]  = t;
        lgate[e * CAP + s] = sG[tid];
        tsel[t * 2 + (tid & 1)]  = e * CAP + s;   // (expert, within-expert slot)
        tgate[t * 2 + (tid & 1)] = sG[tid];
    }
}

// ---------------- We (E,h,d) fp32 -> WeT (E,d,h) bf16 : 64x64 tiles, vectorized ----------------
// (R3: 32x32 scalar version ran at 560 GB/s = ~90us.)
__global__ __launch_bounds__(256) void cast_transpose_we(
    const float* __restrict__ We, __bf16* __restrict__ WeT) {
    __shared__ float t[64][65];    // stride 65: 2-way bank alias only (free, m136)
    const int e  = blockIdx.z;
    const int d0 = blockIdx.x * 64;
    const int h0 = blockIdx.y * 64;
    const int tx = threadIdx.x & 15;
    const int ty = threadIdx.x >> 4;   // 0..15
    const float* src = We + ((size_t)e << 20);
    __bf16* dst = WeT + ((size_t)e << 20);
#pragma unroll
    for (int p = 0; p < 4; ++p) {
        const int row = p * 16 + ty;   // h-local
        const float4 v = *(const float4*)(src + (size_t)(h0 + row) * H + d0 + tx * 4);
        t[row][tx * 4 + 0] = v.x; t[row][tx * 4 + 1] = v.y;
        t[row][tx * 4 + 2] = v.z; t[row][tx * 4 + 3] = v.w;
    }
    __syncthreads();
#pragma unroll
    for (int p = 0; p < 4; ++p) {
        const int drow = p * 16 + ty;  // d-local
        bf16x4 o;
        o[0] = (__bf16)t[tx * 4 + 0][drow];
        o[1] = (__bf16)t[tx * 4 + 1][drow];
        o[2] = (__bf16)t[tx * 4 + 2][drow];
        o[3] = (__bf16)t[tx * 4 + 3][drow];
        *(bf16x4*)(dst + (size_t)(d0 + drow) * H + h0 + tx * 4) = o;
    }
}

// ---------------- grouped GEMM: per expert, gathered rows, 128x128 tile, bf16 MFMA ----------------
// Plain bf16 stores to compacted scratch Eout (no atomics); XOR-swizzled LDS
// (R3: SQ_LDS_BANK_CONFLICT == 0 confirmed).
__global__ __launch_bounds__(256) void moe_gemm(
    const __bf16* __restrict__ Xb, const __bf16* __restrict__ WeT,
    const float* __restrict__ be, const int* __restrict__ cnt,
    const int* __restrict__ ltok, const float* __restrict__ lgate,
    __bf16* __restrict__ Eout) {
    const int e = blockIdx.z;
    const int ne = cnt[e * CNTSTRIDE];
    const int m0 = blockIdx.y * TM;
    if (m0 >= ne) return;              // uniform early-exit for empty tiles
    const int n0 = blockIdx.x * TN;
    int off = 0;
    for (int i2 = 0; i2 < e; ++i2) off += cnt[i2 * CNTSTRIDE];

    __shared__ __align__(16) __bf16 Al[TM * BK];
    __shared__ __align__(16) __bf16 Bl[TN * BK];
    __shared__ int tokL[TM];

    const int tid = threadIdx.x;
    const int lane = tid & 63;
    const int wave = tid >> 6;

    if (tid < TM) {
        const int gi = m0 + tid;
        tokL[tid] = (gi < ne) ? ltok[e * CAP + gi] : 0;   // pad rows read token 0, not stored
    }
    __syncthreads();

    const __bf16* Bt = WeT + ((size_t)e << 20);
    const int qr = lane >> 4;          // quad 0..3
    const int rr = lane & 15;
    const int wr = (wave >> 1) * 64;   // wave's 64x64 quadrant
    const int wc = (wave & 1) * 64;

    f32x4 acc[4][4];
    const f32x4 z = {0.f, 0.f, 0.f, 0.f};
#pragma unroll
    for (int i = 0; i < 4; ++i)
#pragma unroll
        for (int j = 0; j < 4; ++j) acc[i][j] = z;

    const int c0 = tid, c1 = tid + 256;
    const int ar0 = c0 >> 2, ak0 = (((c0 & 3) ^ ((c0 >> 3) & 3)) * 8);
    const int ar1 = c1 >> 2, ak1 = (((c1 & 3) ^ ((c1 >> 3) & 3)) * 8);
    const size_t arow0 = (size_t)tokL[ar0] * H;
    const size_t arow1 = (size_t)tokL[ar1] * H;
    const size_t brow0 = (size_t)(n0 + ar0) * H;
    const size_t brow1 = (size_t)(n0 + ar1) * H;

    for (int k0 = 0; k0 < H; k0 += BK) {
        async16(&Al[c0 * 8], Xb + arow0 + k0 + ak0);
        async16(&Al[c1 * 8], Xb + arow1 + k0 + ak1);
        async16(&Bl[c0 * 8], Bt + brow0 + k0 + ak0);
        async16(&Bl[c1 * 8], Bt + brow1 + k0 + ak1);
        __syncthreads();
        bf16x8 af[4], bfr[4];
#pragma unroll
        for (int i = 0; i < 4; ++i) {
            const int ra = wr + i * 16 + rr;
            af[i] = *(const bf16x8*)&Al[ra * BK + ((qr ^ ((ra >> 1) & 3)) * 8)];
        }
#pragma unroll
        for (int j = 0; j < 4; ++j) {
            const int rb = wc + j * 16 + rr;
            bfr[j] = *(const bf16x8*)&Bl[rb * BK + ((qr ^ ((rb >> 1) & 3)) * 8)];
        }
#pragma unroll
        for (int i = 0; i < 4; ++i)
#pragma unroll
            for (int j = 0; j < 4; ++j)
                acc[i][j] = __builtin_amdgcn_mfma_f32_16x16x32_bf16(af[i], bfr[j], acc[i][j], 0, 0, 0);
        __syncthreads();
    }

    float bev[4];
#pragma unroll
    for (int j = 0; j < 4; ++j) bev[j] = be[e * H + n0 + wc + j * 16 + rr];

    // C/D layout (verified m89/m91): col = lane&15, row = quad*4 + reg
#pragma unroll
    for (int i = 0; i < 4; ++i) {
#pragma unroll
        for (int reg = 0; reg < 4; ++reg) {
            const int rloc = wr + i * 16 + qr * 4 + reg;
            if (m0 + rloc < ne) {
                __bf16* orow = Eout + (size_t)(off + m0 + rloc) * H;
#pragma unroll
                for (int j = 0; j < 4; ++j) {
                    const int d = n0 + wc + j * 16 + rr;
                    orow[d] = (__bf16)(acc[i][j][reg] + bev[j]);
                }
            }
        }
    }
}

// ---------------- combine: wave per token, out[t] = g0*row0 + g1*row1 ----------------
__global__ __launch_bounds__(256) void moe_combine(
    const __bf16* __restrict__ Eout, const int* __restrict__ cnt,
    const int* __restrict__ tsel, const float* __restrict__ tgate,
    float* __restrict__ out) {
    __shared__ int offs[NEXP];
    if (threadIdx.x < NEXP) {
        int o = 0;
        for (int i = 0; i < (int)threadIdx.x; ++i) o += cnt[i * CNTSTRIDE];
        offs[threadIdx.x] = o;
    }
    __syncthreads();
    const int wave = threadIdx.x >> 6, lane = threadIdx.x & 63;
    const int t = blockIdx.x * 4 + wave;
    const int sel0 = tsel[t * 2],  sel1 = tsel[t * 2 + 1];
    const float g0 = tgate[t * 2], g1  = tgate[t * 2 + 1];
    const int e0 = sel0 >> 13, s0 = sel0 & (CAP - 1);
    const int e1 = sel1 >> 13, s1 = sel1 & (CAP - 1);
    const __bf16* r0 = Eout + (size_t)(offs[e0] + s0) * H;
    const __bf16* r1 = Eout + (size_t)(offs[e1] + s1) * H;
    float* orow = out + (size_t)t * H;
#pragma unroll
    for (int c = 0; c < 4; ++c) {
        const int d = c * 256 + lane * 4;
        const bf16x4 a = *(const bf16x4*)(r0 + d);
        const bf16x4 b = *(const bf16x4*)(r1 + d);
        float4 o;
        o.x = g0 * (float)a[0] + g1 * (float)b[0];
        o.y = g0 * (float)a[1] + g1 * (float)b[1];
        o.z = g0 * (float)a[2] + g1 * (float)b[2];
        o.w = g0 * (float)a[3] + g1 * (float)b[3];
        *(float4*)(orow + d) = o;
    }
}

extern "C" void kernel_launch(void* const* d_in, const int* in_sizes, int n_in,
                              void* d_out, int out_size, void* d_ws, size_t ws_size,
                              hipStream_t stream) {
    const float* x  = (const float*)d_in[0];   // (T,H) fp32
    const float* Wg = (const float*)d_in[1];   // (H,E) fp32
    const float* We = (const float*)d_in[2];   // (E,H,H) fp32
    const float* be = (const float*)d_in[3];   // (E,H) fp32
    float* out = (float*)d_out;

    // workspace: Xb 16MiB | WeT 16MiB | Eout 32MiB | meta (~650KB)
    char* ws = (char*)d_ws;
    __bf16* Xb   = (__bf16*)ws;
    __bf16* WeT  = (__bf16*)(ws + ((size_t)16 << 20));
    __bf16* Eout = (__bf16*)(ws + ((size_t)32 << 20));
    char*   meta = ws + ((size_t)64 << 20);
    int*    cnt  = (int*)meta;                               // 8 * 128B
    int*    ltok = (int*)(meta + 1024);
    float*  lgat = (float*)(meta + 1024 + (size_t)NEXP * CAP * 4);
    int*    tsel = (int*)(meta + 1024 + (size_t)NEXP * CAP * 8);
    float*  tgat = (float*)(meta + 1024 + (size_t)NEXP * CAP * 8 + (size_t)T_TOK * 8);

    hipMemsetAsync(cnt, 0, NEXP * CNTSTRIDE * sizeof(int), stream);

    cast_transpose_we<<<dim3(H / 64, H / 64, NEXP), 256, 0, stream>>>(We, WeT);
    moe_route<<<T_TOK / TPB, 256, 0, stream>>>(x, Wg, Xb, cnt, ltok, lgat, tsel, tgat);
    moe_gemm<<<dim3(H / TN, T_TOK / TM, NEXP), 256, 0, stream>>>(Xb, WeT, be, cnt, ltok, lgat, Eout);
    moe_combine<<<T_TOK / 4, 256, 0, stream>>>(Eout, cnt, tsel, tgat, out);
}

// Round 5
// 196.996 us; speedup vs baseline: 2.0312x; 1.0225x over previous
//
#include <hip/hip_runtime.h>
#include <hip/hip_bf16.h>

// Problem constants: B=4,S=2048 -> T=8192 tokens, H=1024, E=8, TOP_K=2
#define H 1024
#define NEXP 8
#define T_TOK 8192
#define CAP 8192      // max entries per expert; also the (e,s) packing radix
#define TM 128
#define TN 128
#define TPB 16        // tokens routed per block (4 per wave) -> 512 blocks
#define CNTSTRIDE 32  // cnt[e*CNTSTRIDE]: one 128B line per expert -> parallel RMW chains

typedef __bf16 bf16x8 __attribute__((ext_vector_type(8)));
typedef __bf16 bf16x4 __attribute__((ext_vector_type(4)));
typedef float f32x4 __attribute__((ext_vector_type(4)));

__device__ __forceinline__ void async16(void* lds, const void* g) {
    __builtin_amdgcn_global_load_lds(
        (const __attribute__((address_space(1))) void*)g,
        (__attribute__((address_space(3))) void*)lds, 16, 0, 0);
}

// ---------------- routing: fp32 logits, top-2, gates; fused x -> bf16 cast ----------------
__global__ __launch_bounds__(256) void moe_route(
    const float* __restrict__ x, const float* __restrict__ Wg,
    __bf16* __restrict__ Xb, int* __restrict__ cnt,
    int* __restrict__ ltok, float* __restrict__ lgate,
    int* __restrict__ tsel, float* __restrict__ tgate) {
    const int tid  = threadIdx.x;
    const int lane = tid & 63;
    const int wave = tid >> 6;
    const int base = blockIdx.x * TPB;

    __shared__ int   sE[TPB * 2];
    __shared__ float sG[TPB * 2];
    __shared__ int   lcnt[NEXP], lbase[NEXP], lslot[TPB * 2];

    for (int i = 0; i < TPB / 4; ++i) {          // 4 tokens per wave
        const int tl = wave * (TPB / 4) + i;
        const int t  = base + tl;
        const float* xr  = x  + (size_t)t * H;
        __bf16*      xbr = Xb + (size_t)t * H;
        float a[NEXP];
#pragma unroll
        for (int e = 0; e < NEXP; ++e) a[e] = 0.f;
#pragma unroll
        for (int j = 0; j < H / 256; ++j) {
            const int h = j * 256 + lane * 4;
            const float4 xv = *(const float4*)(xr + h);
            bf16x4 xo;
            xo[0] = (__bf16)xv.x; xo[1] = (__bf16)xv.y;
            xo[2] = (__bf16)xv.z; xo[3] = (__bf16)xv.w;
            *(bf16x4*)(xbr + h) = xo;
            const float xc[4] = {xv.x, xv.y, xv.z, xv.w};
#pragma unroll
            for (int c = 0; c < 4; ++c) {
                const float4 w0 = *(const float4*)(Wg + (h + c) * NEXP);
                const float4 w1 = *(const float4*)(Wg + (h + c) * NEXP + 4);
                a[0] += xc[c] * w0.x; a[1] += xc[c] * w0.y; a[2] += xc[c] * w0.z; a[3] += xc[c] * w0.w;
                a[4] += xc[c] * w1.x; a[5] += xc[c] * w1.y; a[6] += xc[c] * w1.z; a[7] += xc[c] * w1.w;
            }
        }
#pragma unroll
        for (int e = 0; e < NEXP; ++e) {
#pragma unroll
            for (int off = 32; off > 0; off >>= 1)
                a[e] += __shfl_xor(a[e], off, 64);
        }
        int i0 = 0;
#pragma unroll
        for (int e = 1; e < NEXP; ++e) if (a[e] > a[i0]) i0 = e;   // jax tie-break: lowest idx
        int i1 = (i0 == 0) ? 1 : 0;
#pragma unroll
        for (int e = 0; e < NEXP; ++e) if (e != i0 && a[e] > a[i1]) i1 = e;
        const float ex = __expf(a[i1] - a[i0]);
        const float g0 = 1.f / (1.f + ex);
        const float g1 = ex / (1.f + ex);
        if (lane == 0) {
            sE[tl * 2] = i0; sE[tl * 2 + 1] = i1;
            sG[tl * 2] = g0; sG[tl * 2 + 1] = g1;
        }
    }
    if (tid < NEXP) lcnt[tid] = 0;
    __syncthreads();
    if (tid < TPB * 2) lslot[tid] = atomicAdd(&lcnt[sE[tid]], 1);
    __syncthreads();
    if (tid < NEXP) lbase[tid] = lcnt[tid] ? atomicAdd(&cnt[tid * CNTSTRIDE], lcnt[tid]) : 0;
    __syncthreads();
    if (tid < TPB * 2) {
        const int e = sE[tid];
        const int s = lbase[e] + lslot[tid];
        const int t = base + (tid >> 1);
        ltok[e * CAP + s]  = t;
        lgate[e * CAP + s] = sG[tid];
        tsel[t * 2 + (tid & 1)]  = e * CAP + s;
        tgate[t * 2 + (tid & 1)] = sG[tid];
    }
}

// ---------------- We (E,h,d) fp32 -> WeT (E,d,h) bf16 : 64x64 tiles, vectorized ----------------
__global__ __launch_bounds__(256) void cast_transpose_we(
    const float* __restrict__ We, __bf16* __restrict__ WeT) {
    __shared__ float t[64][65];    // stride 65: 2-way bank alias only (free, m136)
    const int e  = blockIdx.z;
    const int d0 = blockIdx.x * 64;
    const int h0 = blockIdx.y * 64;
    const int tx = threadIdx.x & 15;
    const int ty = threadIdx.x >> 4;   // 0..15
    const float* src = We + ((size_t)e << 20);
    __bf16* dst = WeT + ((size_t)e << 20);
#pragma unroll
    for (int p = 0; p < 4; ++p) {
        const int row = p * 16 + ty;
        const float4 v = *(const float4*)(src + (size_t)(h0 + row) * H + d0 + tx * 4);
        t[row][tx * 4 + 0] = v.x; t[row][tx * 4 + 1] = v.y;
        t[row][tx * 4 + 2] = v.z; t[row][tx * 4 + 3] = v.w;
    }
    __syncthreads();
#pragma unroll
    for (int p = 0; p < 4; ++p) {
        const int drow = p * 16 + ty;
        bf16x4 o;
        o[0] = (__bf16)t[tx * 4 + 0][drow];
        o[1] = (__bf16)t[tx * 4 + 1][drow];
        o[2] = (__bf16)t[tx * 4 + 2][drow];
        o[3] = (__bf16)t[tx * 4 + 3][drow];
        *(bf16x4*)(dst + (size_t)(d0 + drow) * H + h0 + tx * 4) = o;
    }
}

// ---------------- grouped GEMM: 128x128 tile, BK=64 as two BK=32 panels ----------------
// Two panels per operand per k-step (R4: BK=32 gave only 16 MFMA per barrier-drain pair;
// 32 k-iters of vmcnt(0)+s_barrier dominated — MfmaUtil 19%). Each panel keeps the
// R3-verified zero-conflict XOR swizzle and global_load_lds lane-contiguity.
__global__ __launch_bounds__(256) void moe_gemm(
    const __bf16* __restrict__ Xb, const __bf16* __restrict__ WeT,
    const float* __restrict__ be, const int* __restrict__ cnt,
    const int* __restrict__ ltok, const float* __restrict__ lgate,
    __bf16* __restrict__ Eout) {
    const int e = blockIdx.z;
    const int ne = cnt[e * CNTSTRIDE];
    const int m0 = blockIdx.y * TM;
    if (m0 >= ne) return;
    const int n0 = blockIdx.x * TN;
    int off = 0;
    for (int i2 = 0; i2 < e; ++i2) off += cnt[i2 * CNTSTRIDE];

    __shared__ __align__(16) __bf16 Al [TM * 32];
    __shared__ __align__(16) __bf16 Al2[TM * 32];
    __shared__ __align__(16) __bf16 Bl [TN * 32];
    __shared__ __align__(16) __bf16 Bl2[TN * 32];
    __shared__ int tokL[TM];

    const int tid = threadIdx.x;
    const int lane = tid & 63;
    const int wave = tid >> 6;

    if (tid < TM) {
        const int gi = m0 + tid;
        tokL[tid] = (gi < ne) ? ltok[e * CAP + gi] : 0;
    }
    __syncthreads();

    const __bf16* Bt = WeT + ((size_t)e << 20);
    const int qr = lane >> 4;
    const int rr = lane & 15;
    const int wr = (wave >> 1) * 64;
    const int wc = (wave & 1) * 64;

    f32x4 acc[4][4];
    const f32x4 z = {0.f, 0.f, 0.f, 0.f};
#pragma unroll
    for (int i = 0; i < 4; ++i)
#pragma unroll
        for (int j = 0; j < 4; ++j) acc[i][j] = z;

    // per-panel: 512 chunks of 16B; thread covers c0=tid, c1=tid+256 (wave-contiguous LDS)
    const int c0 = tid, c1 = tid + 256;
    const int ar0 = c0 >> 2, ak0 = (((c0 & 3) ^ ((c0 >> 3) & 3)) * 8);
    const int ar1 = c1 >> 2, ak1 = (((c1 & 3) ^ ((c1 >> 3) & 3)) * 8);
    const size_t arow0 = (size_t)tokL[ar0] * H;
    const size_t arow1 = (size_t)tokL[ar1] * H;
    const size_t brow0 = (size_t)(n0 + ar0) * H;
    const size_t brow1 = (size_t)(n0 + ar1) * H;

    for (int k0 = 0; k0 < H; k0 += 64) {
        async16(&Al [c0 * 8], Xb + arow0 + k0 + ak0);
        async16(&Al [c1 * 8], Xb + arow1 + k0 + ak1);
        async16(&Al2[c0 * 8], Xb + arow0 + k0 + 32 + ak0);
        async16(&Al2[c1 * 8], Xb + arow1 + k0 + 32 + ak1);
        async16(&Bl [c0 * 8], Bt + brow0 + k0 + ak0);
        async16(&Bl [c1 * 8], Bt + brow1 + k0 + ak1);
        async16(&Bl2[c0 * 8], Bt + brow0 + k0 + 32 + ak0);
        async16(&Bl2[c1 * 8], Bt + brow1 + k0 + 32 + ak1);
        __syncthreads();
        {
            bf16x8 af[4], bfr[4];
#pragma unroll
            for (int i = 0; i < 4; ++i) {
                const int ra = wr + i * 16 + rr;
                af[i] = *(const bf16x8*)&Al[ra * 32 + ((qr ^ ((ra >> 1) & 3)) * 8)];
            }
#pragma unroll
            for (int j = 0; j < 4; ++j) {
                const int rb = wc + j * 16 + rr;
                bfr[j] = *(const bf16x8*)&Bl[rb * 32 + ((qr ^ ((rb >> 1) & 3)) * 8)];
            }
#pragma unroll
            for (int i = 0; i < 4; ++i)
#pragma unroll
                for (int j = 0; j < 4; ++j)
                    acc[i][j] = __builtin_amdgcn_mfma_f32_16x16x32_bf16(af[i], bfr[j], acc[i][j], 0, 0, 0);
        }
        {
            bf16x8 af[4], bfr[4];
#pragma unroll
            for (int i = 0; i < 4; ++i) {
                const int ra = wr + i * 16 + rr;
                af[i] = *(const bf16x8*)&Al2[ra * 32 + ((qr ^ ((ra >> 1) & 3)) * 8)];
            }
#pragma unroll
            for (int j = 0; j < 4; ++j) {
                const int rb = wc + j * 16 + rr;
                bfr[j] = *(const bf16x8*)&Bl2[rb * 32 + ((qr ^ ((rb >> 1) & 3)) * 8)];
            }
#pragma unroll
            for (int i = 0; i < 4; ++i)
#pragma unroll
                for (int j = 0; j < 4; ++j)
                    acc[i][j] = __builtin_amdgcn_mfma_f32_16x16x32_bf16(af[i], bfr[j], acc[i][j], 0, 0, 0);
        }
        __syncthreads();
    }

    float bev[4];
#pragma unroll
    for (int j = 0; j < 4; ++j) bev[j] = be[e * H + n0 + wc + j * 16 + rr];

    // C/D layout (verified m89/m91): col = lane&15, row = quad*4 + reg
#pragma unroll
    for (int i = 0; i < 4; ++i) {
#pragma unroll
        for (int reg = 0; reg < 4; ++reg) {
            const int rloc = wr + i * 16 + qr * 4 + reg;
            if (m0 + rloc < ne) {
                __bf16* orow = Eout + (size_t)(off + m0 + rloc) * H;
#pragma unroll
                for (int j = 0; j < 4; ++j) {
                    const int d = n0 + wc + j * 16 + rr;
                    orow[d] = (__bf16)(acc[i][j][reg] + bev[j]);
                }
            }
        }
    }
}

// ---------------- combine: wave per token, out[t] = g0*row0 + g1*row1 ----------------
__global__ __launch_bounds__(256) void moe_combine(
    const __bf16* __restrict__ Eout, const int* __restrict__ cnt,
    const int* __restrict__ tsel, const float* __restrict__ tgate,
    float* __restrict__ out) {
    __shared__ int offs[NEXP];
    if (threadIdx.x < NEXP) {
        int o = 0;
        for (int i = 0; i < (int)threadIdx.x; ++i) o += cnt[i * CNTSTRIDE];
        offs[threadIdx.x] = o;
    }
    __syncthreads();
    const int wave = threadIdx.x >> 6, lane = threadIdx.x & 63;
    const int t = blockIdx.x * 4 + wave;
    const int sel0 = tsel[t * 2],  sel1 = tsel[t * 2 + 1];
    const float g0 = tgate[t * 2], g1  = tgate[t * 2 + 1];
    const int e0 = sel0 >> 13, s0 = sel0 & (CAP - 1);
    const int e1 = sel1 >> 13, s1 = sel1 & (CAP - 1);
    const __bf16* r0 = Eout + (size_t)(offs[e0] + s0) * H;
    const __bf16* r1 = Eout + (size_t)(offs[e1] + s1) * H;
    float* orow = out + (size_t)t * H;
#pragma unroll
    for (int c = 0; c < 4; ++c) {
        const int d = c * 256 + lane * 4;
        const bf16x4 a = *(const bf16x4*)(r0 + d);
        const bf16x4 b = *(const bf16x4*)(r1 + d);
        float4 o;
        o.x = g0 * (float)a[0] + g1 * (float)b[0];
        o.y = g0 * (float)a[1] + g1 * (float)b[1];
        o.z = g0 * (float)a[2] + g1 * (float)b[2];
        o.w = g0 * (float)a[3] + g1 * (float)b[3];
        *(float4*)(orow + d) = o;
    }
}

extern "C" void kernel_launch(void* const* d_in, const int* in_sizes, int n_in,
                              void* d_out, int out_size, void* d_ws, size_t ws_size,
                              hipStream_t stream) {
    const float* x  = (const float*)d_in[0];   // (T,H) fp32
    const float* Wg = (const float*)d_in[1];   // (H,E) fp32
    const float* We = (const float*)d_in[2];   // (E,H,H) fp32
    const float* be = (const float*)d_in[3];   // (E,H) fp32
    float* out = (float*)d_out;

    // workspace: Xb 16MiB | WeT 16MiB | Eout 32MiB | meta
    char* ws = (char*)d_ws;
    __bf16* Xb   = (__bf16*)ws;
    __bf16* WeT  = (__bf16*)(ws + ((size_t)16 << 20));
    __bf16* Eout = (__bf16*)(ws + ((size_t)32 << 20));
    char*   meta = ws + ((size_t)64 << 20);
    int*    cnt  = (int*)meta;                               // 8 * 128B
    int*    ltok = (int*)(meta + 1024);
    float*  lgat = (float*)(meta + 1024 + (size_t)NEXP * CAP * 4);
    int*    tsel = (int*)(meta + 1024 + (size_t)NEXP * CAP * 8);
    float*  tgat = (float*)(meta + 1024 + (size_t)NEXP * CAP * 8 + (size_t)T_TOK * 8);

    hipMemsetAsync(cnt, 0, NEXP * CNTSTRIDE * sizeof(int), stream);

    cast_transpose_we<<<dim3(H / 64, H / 64, NEXP), 256, 0, stream>>>(We, WeT);
    moe_route<<<T_TOK / TPB, 256, 0, stream>>>(x, Wg, Xb, cnt, ltok, lgat, tsel, tgat);
    moe_gemm<<<dim3(H / TN, T_TOK / TM, NEXP), 256, 0, stream>>>(Xb, WeT, be, cnt, ltok, lgat, Eout);
    moe_combine<<<T_TOK / 4, 256, 0, stream>>>(Eout, cnt, tsel, tgat, out);
}